// Round 4
// baseline (332.941 us; speedup 1.0000x reference)
//
#include <hip/hip_runtime.h>
#include <cstddef>

#define PB 4096  // points per batch
static constexpr float SCALE_F = 0.17677669529663687f;  // 32^-0.5

typedef __attribute__((ext_vector_type(8))) short bf16x8;
typedef __attribute__((ext_vector_type(4))) float f32x4;

static __device__ __forceinline__ unsigned short f2bf(float x) {
  unsigned u = __builtin_bit_cast(unsigned, x);
  u += 0x7fffu + ((u >> 16) & 1u);  // RNE
  return (unsigned short)(u >> 16);
}
static __device__ __forceinline__ float bf2f(unsigned short h) {
  return __builtin_bit_cast(float, (unsigned)h << 16);
}

// ---------------------------------------------------------------------------
// kNN: one wave per query; sorted top-32 distributed over lanes 0..31.
// fp32 distances with explicit rounding = exactly the reference's arithmetic.
// ---------------------------------------------------------------------------
__global__ __launch_bounds__(64) void knn_kernel(const float* __restrict__ xyz,
                                                 int* __restrict__ idx_out) {
  const int g = blockIdx.x;          // 0 .. B*PB-1
  const int b = g >> 12;
  const int p = g & (PB - 1);
  const int lane = threadIdx.x;
  const float* base = xyz + (size_t)b * PB * 3;
  const float qx = base[p * 3 + 0];
  const float qy = base[p * 3 + 1];
  const float qz = base[p * 3 + 2];
  float list_d = 3.4e38f;  // lanes 0..31 hold the sorted list
  int list_i = -1;
  for (int c = 0; c < PB / 64; ++c) {
    const int j = (c << 6) + lane;
    const float dx = __fsub_rn(qx, base[j * 3 + 0]);
    const float dy = __fsub_rn(qy, base[j * 3 + 1]);
    const float dz = __fsub_rn(qz, base[j * 3 + 2]);
    const float d2 = __fadd_rn(__fadd_rn(__fmul_rn(dx, dx), __fmul_rn(dy, dy)),
                               __fmul_rn(dz, dz));
    float worst = __shfl(list_d, 31);
    unsigned long long mask = __ballot(d2 < worst);
    while (mask) {
      const int l = __ffsll(mask) - 1;
      mask &= mask - 1;
      const float v = __shfl(d2, l);
      worst = __shfl(list_d, 31);
      if (v < worst) {
        const unsigned long long gt = __ballot((lane < 32) && (list_d > v));
        const int pos = __ffsll(gt) - 1;
        const float pd = __shfl_up(list_d, 1);
        const int pi = __shfl_up(list_i, 1);
        if (lane < 32 && lane >= pos) {
          const bool at = (lane == pos);
          list_d = at ? v : pd;
          list_i = at ? ((c << 6) + l) : pi;
        }
      }
    }
  }
  if (lane < 32) idx_out[(size_t)g * 32 + lane] = list_i;
}

// ---------------------------------------------------------------------------
// Weight prep: bf16 hi/lo split of Wq,Wk,Wv,W2,Wp (row-major, K-contiguous).
// ---------------------------------------------------------------------------
__global__ __launch_bounds__(256) void prep_w(
    const float* __restrict__ Wq, const float* __restrict__ Wk,
    const float* __restrict__ Wv, const float* __restrict__ W2,
    const float* __restrict__ Wp,
    unsigned short* __restrict__ whi, unsigned short* __restrict__ wlo) {
  const int e = blockIdx.x * 256 + threadIdx.x;   // 0 .. 327679
  const int m = e >> 16;
  const int off = e & 65535;
  const float* src = (m == 0) ? Wq : (m == 1) ? Wk : (m == 2) ? Wv
                     : (m == 3) ? W2 : Wp;
  const float x = src[off];
  const unsigned short hi = f2bf(x);
  whi[e] = hi;
  wlo[e] = f2bf(x - bf2f(hi));
}

// ---------------------------------------------------------------------------
// bf16x3 MFMA GEMM: C[r0..r0+31][:] = A @ W^T (+bias).
// ---------------------------------------------------------------------------
static __device__ __forceinline__ void gemm32_mfma(
    const float* __restrict__ A, const unsigned short* __restrict__ wh,
    const unsigned short* __restrict__ wl, const float* __restrict__ bias,
    float* __restrict__ C, const int r0,
    unsigned short* ah, unsigned short* al) {
  const int tid = threadIdx.x;
#pragma unroll
  for (int t = 0; t < 8; ++t) {
    const int idx4 = (t << 8) + tid;     // 2048 float4-slots = 32 rows x 64
    const int row = idx4 >> 6;
    const int c4 = idx4 & 63;
    const float4 v = *(const float4*)(A + (size_t)(r0 + row) * 256 + (c4 << 2));
    const unsigned short h0 = f2bf(v.x), h1 = f2bf(v.y);
    const unsigned short h2 = f2bf(v.z), h3 = f2bf(v.w);
    const unsigned short l0 = f2bf(v.x - bf2f(h0)), l1 = f2bf(v.y - bf2f(h1));
    const unsigned short l2 = f2bf(v.z - bf2f(h2)), l3 = f2bf(v.w - bf2f(h3));
    const int base = (row << 9) + ((c4 << 3) ^ ((row & 7) << 4));
    *(uint2*)((char*)ah + base) =
        make_uint2((unsigned)h0 | ((unsigned)h1 << 16),
                   (unsigned)h2 | ((unsigned)h3 << 16));
    *(uint2*)((char*)al + base) =
        make_uint2((unsigned)l0 | ((unsigned)l1 << 16),
                   (unsigned)l2 | ((unsigned)l3 << 16));
  }
  __syncthreads();
  const int lane = tid & 63;
  const int w = tid >> 6;
  const int il = lane & 15;
  const int q4 = lane >> 4;
  f32x4 acc[2][4];
#pragma unroll
  for (int mt = 0; mt < 2; ++mt)
#pragma unroll
    for (int nt = 0; nt < 4; ++nt) acc[mt][nt] = (f32x4){0.f, 0.f, 0.f, 0.f};
#pragma unroll 2
  for (int ks = 0; ks < 8; ++ks) {
    bf16x8 bh[4], bl[4], a0[2], a1[2];
#pragma unroll
    for (int nt = 0; nt < 4; ++nt) {
      const int n = (w << 6) + (nt << 4) + il;
      const size_t off = (size_t)n * 256 + (ks << 5) + (q4 << 3);
      bh[nt] = *(const bf16x8*)(wh + off);
      bl[nt] = *(const bf16x8*)(wl + off);
    }
#pragma unroll
    for (int mt = 0; mt < 2; ++mt) {
      const int row = (mt << 4) + il;
      const int byte = (row << 9) + ((((ks << 5) + (q4 << 3)) << 1) ^ ((row & 7) << 4));
      a0[mt] = *(const bf16x8*)((const char*)ah + byte);
      a1[mt] = *(const bf16x8*)((const char*)al + byte);
    }
#pragma unroll
    for (int mt = 0; mt < 2; ++mt)
#pragma unroll
      for (int nt = 0; nt < 4; ++nt) {
        acc[mt][nt] = __builtin_amdgcn_mfma_f32_16x16x32_bf16(a0[mt], bh[nt], acc[mt][nt], 0, 0, 0);
        acc[mt][nt] = __builtin_amdgcn_mfma_f32_16x16x32_bf16(a1[mt], bh[nt], acc[mt][nt], 0, 0, 0);
        acc[mt][nt] = __builtin_amdgcn_mfma_f32_16x16x32_bf16(a0[mt], bl[nt], acc[mt][nt], 0, 0, 0);
      }
  }
#pragma unroll
  for (int mt = 0; mt < 2; ++mt)
#pragma unroll
    for (int nt = 0; nt < 4; ++nt) {
      const int col = (w << 6) + (nt << 4) + il;
      const float bv = bias ? bias[col] : 0.f;
#pragma unroll
      for (int r = 0; r < 4; ++r)
        C[(size_t)(r0 + (mt << 4) + (q4 << 2) + r) * 256 + col] = acc[mt][nt][r] + bv;
    }
}

__global__ __launch_bounds__(256) void qkv_mfma(
    const float* __restrict__ feats,
    const unsigned short* __restrict__ whi, const unsigned short* __restrict__ wlo,
    float* __restrict__ qb, float* __restrict__ kb, float* __restrict__ vb) {
  __shared__ unsigned short ah[32 * 256];
  __shared__ unsigned short al[32 * 256];
  const int bid = blockIdx.x;
  const int sel = bid % 3;
  const int r0 = (bid / 3) << 5;
  const unsigned short* wh = whi + (size_t)sel * 65536;
  const unsigned short* wl = wlo + (size_t)sel * 65536;
  float* C = (sel == 0) ? qb : (sel == 1) ? kb : vb;
  gemm32_mfma(feats, wh, wl, nullptr, C, r0, ah, al);
}

__global__ __launch_bounds__(256) void proj_mfma(
    const float* __restrict__ A,
    const unsigned short* __restrict__ whi, const unsigned short* __restrict__ wlo,
    const float* __restrict__ bp, float* __restrict__ C) {
  __shared__ unsigned short ah[32 * 256];
  __shared__ unsigned short al[32 * 256];
  gemm32_mfma(A, whi, wlo, bp, C, blockIdx.x << 5, ah, al);
}

// ---------------------------------------------------------------------------
// MFMA fused kernel: ONE point per block, 256 threads = 4 waves, each wave
// owns 64 N-cols (2 heads). acc[2 mt][4 nt] f32x4 = 32 VGPR. ~20KB LDS ->
// up to 8 blocks/CU resident: cross-block phase overlap hides gather latency.
// D-layout: m = mt*16 + q4*4 + r (neighbor), n = w*64 + nt*16 + il (dim).
// ---------------------------------------------------------------------------
__global__ __launch_bounds__(256) void fused_kernel(
    const float* __restrict__ xyz, const int* __restrict__ nbr_idx,
    const float* __restrict__ qbuf, const float* __restrict__ kbuf,
    const float* __restrict__ vbuf,
    const float* __restrict__ W1, const float* __restrict__ b1,
    const unsigned short* __restrict__ w2hi, const float* __restrict__ b2,
    float* __restrict__ o_pre) {
  __shared__ unsigned short h_lds[32 * 256];  // 16 KB, swizzled
  __shared__ float q_lds[256];
  __shared__ float rel[32][3];
  __shared__ int nbr[32];
  __shared__ float sc_lds[32][9];
  __shared__ float at_lds[32][9];

  const int g = blockIdx.x;          // 0 .. 8191 (one point)
  const int b = g >> 12;
  const int p = g & (PB - 1);
  const int tid = threadIdx.x;

  // ---- phase 0: neighbors, relpos, q
  if (tid < 32) {
    const int j = nbr_idx[(size_t)g * 32 + tid];
    nbr[tid] = j;
    const float* xb = xyz + (size_t)b * PB * 3;
    rel[tid][0] = xb[j * 3 + 0] - xb[p * 3 + 0];
    rel[tid][1] = xb[j * 3 + 1] - xb[p * 3 + 1];
    rel[tid][2] = xb[j * 3 + 2] - xb[p * 3 + 2];
  }
  q_lds[tid] = qbuf[(size_t)g * 256 + tid];
  __syncthreads();

  // ---- phase 1: h = relu(relpos @ W1^T + b1) -> LDS bf16 (swizzled)
  {
    const int half = tid >> 7;        // rows 16*half .. 16*half+15
    const int c0 = (tid & 127) << 1;  // column pair
    const float w00 = W1[c0 * 3 + 0], w01 = W1[c0 * 3 + 1], w02 = W1[c0 * 3 + 2];
    const float w10 = W1[c0 * 3 + 3], w11 = W1[c0 * 3 + 4], w12 = W1[c0 * 3 + 5];
    const float bb0 = b1[c0], bb1 = b1[c0 + 1];
#pragma unroll 4
    for (int rl = 0; rl < 16; ++rl) {
      const int rr = (half << 4) + rl;
      const float rx = rel[rr][0], ry = rel[rr][1], rz = rel[rr][2];
      const float h0 = fmaxf(bb0 + rx * w00 + ry * w01 + rz * w02, 0.f);
      const float h1 = fmaxf(bb1 + rx * w10 + ry * w11 + rz * w12, 0.f);
      const unsigned pk = (unsigned)f2bf(h0) | ((unsigned)f2bf(h1) << 16);
      *(unsigned*)((char*)h_lds + (rr << 9) + (((unsigned)c0 << 1) ^ ((rr & 7) << 4))) = pk;
    }
  }
  __syncthreads();

  const int lane = tid & 63;
  const int w = tid >> 6;           // wave id: cols w*64..w*64+63 (heads 2w,2w+1)
  const int il = lane & 15;
  const int q4 = lane >> 4;

  // ---- phase 2: pos_bias MFMA over K=256
  f32x4 acc[2][4];
#pragma unroll
  for (int mt = 0; mt < 2; ++mt)
#pragma unroll
    for (int nt = 0; nt < 4; ++nt) acc[mt][nt] = (f32x4){0.f, 0.f, 0.f, 0.f};
#pragma unroll 2
  for (int ks = 0; ks < 8; ++ks) {
    bf16x8 bfr[4], afr[2];
#pragma unroll
    for (int nt = 0; nt < 4; ++nt) {
      const int n = (w << 6) + (nt << 4) + il;
      bfr[nt] = *(const bf16x8*)(w2hi + (size_t)n * 256 + (ks << 5) + (q4 << 3));
    }
#pragma unroll
    for (int mt = 0; mt < 2; ++mt) {
      const int row = (mt << 4) + il;
      const int byte = (row << 9) + ((((ks << 5) + (q4 << 3)) << 1) ^ ((row & 7) << 4));
      afr[mt] = *(const bf16x8*)((const char*)h_lds + byte);
    }
#pragma unroll
    for (int mt = 0; mt < 2; ++mt)
#pragma unroll
      for (int nt = 0; nt < 4; ++nt)
        acc[mt][nt] = __builtin_amdgcn_mfma_f32_16x16x32_bf16(
            afr[mt], bfr[nt], acc[mt][nt], 0, 0, 0);
  }
#pragma unroll
  for (int nt = 0; nt < 4; ++nt) {
    const float bv = b2[(w << 6) + (nt << 4) + il];
#pragma unroll
    for (int mt = 0; mt < 2; ++mt)
#pragma unroll
      for (int r = 0; r < 4; ++r) acc[mt][nt][r] += bv;
  }

  const size_t kvbase = (size_t)(b << 12) * 256;
  // q values for this thread's 4 dims (fixed across neighbors)
  float qv[4];
#pragma unroll
  for (int nt = 0; nt < 4; ++nt) qv[nt] = q_lds[(w << 6) + (nt << 4) + il];

  // ---- phase 3: scores; wave covers heads 2w (nt 0,1) and 2w+1 (nt 2,3)
#pragma unroll
  for (int mt = 0; mt < 2; ++mt) {
#pragma unroll
    for (int r = 0; r < 4; ++r) {
      const int k = (mt << 4) + (q4 << 2) + r;
      const int j = nbr[k];
      const float* krow = kbuf + kvbase + (size_t)j * 256;
      float sA = 0.f, sB = 0.f;
#pragma unroll
      for (int nt = 0; nt < 4; ++nt) {
        const int d = (w << 6) + (nt << 4) + il;
        const float t = qv[nt] * (krow[d] + acc[mt][nt][r]);
        if (nt < 2) sA += t; else sB += t;
      }
#pragma unroll
      for (int off = 1; off <= 8; off <<= 1) {
        sA += __shfl_xor(sA, off);
        sB += __shfl_xor(sB, off);
      }
      if (il == 0) {
        sc_lds[k][(w << 1)]     = sA * SCALE_F;
        sc_lds[k][(w << 1) + 1] = sB * SCALE_F;
      }
    }
  }
  __syncthreads();

  // ---- phase 4: softmax over K=32 per head; 256 threads = 32 x 8 exactly
  {
    const int kk = tid & 31;
    const int head = tid >> 5;
    const float val = sc_lds[kk][head];
    float m = val;
#pragma unroll
    for (int off = 16; off; off >>= 1) m = fmaxf(m, __shfl_xor(m, off));
    const float e = __expf(val - m);
    float ssum = e;
#pragma unroll
    for (int off = 16; off; off >>= 1) ssum += __shfl_xor(ssum, off);
    at_lds[kk][head] = e / ssum;
  }
  __syncthreads();

  // ---- phase 5: out = sum_k attn * (v_nei + pb)
  float o[4];
#pragma unroll
  for (int nt = 0; nt < 4; ++nt) o[nt] = 0.f;
#pragma unroll
  for (int mt = 0; mt < 2; ++mt) {
#pragma unroll
    for (int r = 0; r < 4; ++r) {
      const int k = (mt << 4) + (q4 << 2) + r;
      const int j = nbr[k];
      const float* vrow = vbuf + kvbase + (size_t)j * 256;
      const float awA = at_lds[k][(w << 1)];
      const float awB = at_lds[k][(w << 1) + 1];
#pragma unroll
      for (int nt = 0; nt < 4; ++nt) {
        const int d = (w << 6) + (nt << 4) + il;
        const float aw = (nt < 2) ? awA : awB;
        o[nt] += aw * (vrow[d] + acc[mt][nt][r]);
      }
    }
  }
#pragma unroll
  for (int nt = 0; nt < 4; ++nt) {
    float v = o[nt];
    v += __shfl_xor(v, 16);
    v += __shfl_xor(v, 32);
    if (q4 == 0)
      o_pre[(size_t)g * 256 + (w << 6) + (nt << 4) + il] = v;
  }
}

// ---------------------------------------------------------------------------
extern "C" void kernel_launch(void* const* d_in, const int* in_sizes, int n_in,
                              void* d_out, int out_size, void* d_ws, size_t ws_size,
                              hipStream_t stream) {
  (void)in_sizes; (void)n_in; (void)out_size; (void)ws_size;
  const float* xyz   = (const float*)d_in[0];
  const float* feats = (const float*)d_in[1];
  const float* Wq    = (const float*)d_in[2];
  const float* Wk    = (const float*)d_in[3];
  const float* Wv    = (const float*)d_in[4];
  const float* Wp    = (const float*)d_in[5];
  const float* bp    = (const float*)d_in[6];
  const float* W1    = (const float*)d_in[7];
  const float* b1    = (const float*)d_in[8];
  const float* W2    = (const float*)d_in[9];
  const float* b2    = (const float*)d_in[10];
  float* out = (float*)d_out;

  // ws floats: [idx:262144][q:2M][k:2M][v:2M][op:2M][whi:163840][wlo:163840]
  int* idxw  = (int*)d_ws;
  float* wsf = (float*)d_ws;
  float* qb = wsf + 262144;
  float* kb = qb + 2097152;
  float* vb = kb + 2097152;
  float* op = vb + 2097152;
  unsigned short* whi = (unsigned short*)(op + 2097152);
  unsigned short* wlo = whi + 327680;

  hipLaunchKernelGGL(prep_w, dim3(1280), dim3(256), 0, stream,
                     Wq, Wk, Wv, W2, Wp, whi, wlo);
  hipLaunchKernelGGL(knn_kernel, dim3(2 * PB), dim3(64), 0, stream, xyz, idxw);
  hipLaunchKernelGGL(qkv_mfma, dim3(768), dim3(256), 0, stream,
                     feats, whi, wlo, qb, kb, vb);
  hipLaunchKernelGGL(fused_kernel, dim3(2 * PB), dim3(256), 0, stream,
                     xyz, idxw, qb, kb, vb, W1, b1,
                     whi + (size_t)3 * 65536, b2, op);
  hipLaunchKernelGGL(proj_mfma, dim3(256), dim3(256), 0, stream,
                     op, whi + (size_t)4 * 65536, wlo + (size_t)4 * 65536, bp, out);
}